// Round 2
// baseline (578.306 us; speedup 1.0000x reference)
//
#include <hip/hip_runtime.h>

#define BB 8
#define NN 16384
#define DIMD 512
#define MVV 8
#define SCALE_C 0.1f
#define EPS_C 1e-5f

typedef unsigned int u32;

// load 8 contiguous fp32 (16B aligned) -> 8 fp32
__device__ __forceinline__ void load8f(const float* __restrict__ p, float* f) {
    float4 a = *(const float4*)p;
    float4 b = *(const float4*)(p + 4);
    f[0] = a.x; f[1] = a.y; f[2] = a.z; f[3] = a.w;
    f[4] = b.x; f[5] = b.y; f[6] = b.z; f[7] = b.w;
}

__global__ __launch_bounds__(256) void kzero(float* __restrict__ p, int n) {
    int i = blockIdx.x * 256 + threadIdx.x;
    if (i < n) p[i] = 0.0f;
}

// Pass 1: column sums of x over N, per batch. grid (128, 8), block 256.
__global__ __launch_bounds__(256) void kmean(const float* __restrict__ x, float* __restrict__ wsum) {
    const int b = blockIdx.y;
    const int chunk = blockIdx.x;           // 0..127
    const int t = threadIdx.x;
    const int c = t & 63;                   // d-chunk (8 d's)
    const int rt = t >> 6;                  // wave id 0..3
    const int rowsPerBlock = NN / 128;      // 128
    const long base = ((long)b * NN + (long)chunk * rowsPerBlock) * DIMD;

    float acc[8];
#pragma unroll
    for (int j = 0; j < 8; j++) acc[j] = 0.0f;

    for (int r = rt; r < rowsPerBlock; r += 4) {
        const float* p = x + base + (long)r * DIMD + c * 8;
        float f[8];
        load8f(p, f);
#pragma unroll
        for (int j = 0; j < 8; j++) acc[j] += f[j];
    }

    __shared__ float red[256][9];  // +1 pad against bank conflicts
#pragma unroll
    for (int j = 0; j < 8; j++) red[t][j] = acc[j];
    __syncthreads();

    if (t < 64) {
        float s[8];
#pragma unroll
        for (int j = 0; j < 8; j++)
            s[j] = red[t][j] + red[t + 64][j] + red[t + 128][j] + red[t + 192][j];
        float* dst = wsum + b * DIMD + t * 8;
#pragma unroll
        for (int j = 0; j < 8; j++) atomicAdd(dst + j, s[j]);
    }
}

// Pass 2: fold mean-field through Cayley into per-batch WoT[d][i], c2[d].
// grid 8 (one block per b), block 64 (one wave).
__global__ __launch_bounds__(64) void kfold(const float* __restrict__ wsum,
                                            const float* __restrict__ Wm,
                                            const float* __restrict__ bm,
                                            const float* __restrict__ Wo,
                                            const float* __restrict__ bo,
                                            const float* __restrict__ bp,
                                            float* __restrict__ wot,
                                            float* __restrict__ c2) {
    const int b = blockIdx.x;
    const int l = threadIdx.x;
    const float invN = 1.0f / (float)NN;

    float m[8];
#pragma unroll
    for (int j = 0; j < 8; j++) m[j] = wsum[b * DIMD + l * 8 + j] * invN;

    // mf[i] = dot(mean_field, Wm[i,:]) + bm[i], broadcast via butterfly
    float mf[8];
#pragma unroll
    for (int i = 0; i < 8; i++) {
        float wmr[8];
        load8f(Wm + i * DIMD + l * 8, wmr);
        float p = 0.0f;
#pragma unroll
        for (int j = 0; j < 8; j++) p += m[j] * wmr[j];
#pragma unroll
        for (int off = 32; off >= 1; off >>= 1) p += __shfl_xor(p, off, 64);
        mf[i] = p + bm[i];
    }

    // T[i][k] = sum_j C[i,j,k] * mf[j]  (C has exactly one j per (i,k))
    const int masks[8] = {0, 1, 2, 4, 3, 5, 6, 7};
    const int invm[8]  = {0, 1, 2, 4, 3, 5, 6, 7};  // mask -> index
    float T[8][8];
#pragma unroll
    for (int i = 0; i < 8; i++) {
#pragma unroll
        for (int k = 0; k < 8; k++) {
            int bmask = masks[i] ^ masks[k];
            int j = invm[bmask];
            int s = 0, aa = masks[i] >> 1;
            while (aa) { s += __popc(aa & bmask); aa >>= 1; }
            T[i][k] = (s & 1) ? -mf[j] : mf[j];
        }
    }

    // cvec[k] = sum_i bp[i] * T[i][k]
    float cv[8];
#pragma unroll
    for (int k = 0; k < 8; k++) {
        float s = 0.0f;
#pragma unroll
        for (int i = 0; i < 8; i++) s += bp[i] * T[i][k];
        cv[k] = s;
    }

    // per-lane: 8 rows d = l*8 + j
#pragma unroll
    for (int j = 0; j < 8; j++) {
        int d = l * 8 + j;
        float wor[8];
        load8f(Wo + d * 8, wor);  // Wo[d][k], contiguous
        float cc = bo[d];
#pragma unroll
        for (int k = 0; k < 8; k++) cc += cv[k] * wor[k];
        c2[b * DIMD + d] = cc;
#pragma unroll
        for (int i = 0; i < 8; i++) {
            float s = 0.0f;
#pragma unroll
            for (int k = 0; k < 8; k++) s += T[i][k] * wor[k];
            wot[((long)b * DIMD + d) * 8 + i] = s;
        }
    }
}

// Pass 3: main streaming pass. One wave per token; lane l owns d in [8l, 8l+8).
// grid (128, 8), block 256 (4 waves).
__global__ __launch_bounds__(256, 2) void kmain(const float* __restrict__ x,
                                                const float* __restrict__ Wp,
                                                const float* __restrict__ gamma,
                                                const float* __restrict__ beta,
                                                const float* __restrict__ wot,
                                                const float* __restrict__ c2,
                                                float* __restrict__ out) {
    const int b = blockIdx.y;
    const int chunk = blockIdx.x;            // 0..127
    const int w = threadIdx.x >> 6;          // wave 0..3
    const int l = threadIdx.x & 63;
    const int d0 = l * 8;

    // persistent per-lane weights
    float wp[8][8];
#pragma unroll
    for (int i = 0; i < 8; i++) load8f(Wp + i * DIMD + d0, wp[i]);

    float wo[8][8];  // wo[j][i] = WoT[b, d0+j, i]
    const float* wotp = wot + ((long)b * DIMD + d0) * 8;
#pragma unroll
    for (int j = 0; j < 8; j++)
#pragma unroll
        for (int i = 0; i < 8; i++) wo[j][i] = wotp[j * 8 + i];

    float cc[8];
#pragma unroll
    for (int j = 0; j < 8; j++) cc[j] = c2[b * DIMD + d0 + j];

    float g[8], be[8];
    load8f(gamma + d0, g);
    load8f(beta + d0, be);

    const int rowsPerBlock = NN / 128;       // 128
    const long rowbase = (long)b * NN + (long)chunk * rowsPerBlock;

    for (int r = w; r < rowsPerBlock; r += 4) {
        const float* px = x + (rowbase + r) * DIMD + d0;
        float xv[8];
        load8f(px, xv);

        // pm[i] partial = sum over my 8 d's
        float pm[8];
#pragma unroll
        for (int i = 0; i < 8; i++) {
            float p = xv[0] * wp[i][0];
#pragma unroll
            for (int j = 1; j < 8; j++) p += xv[j] * wp[i][j];
            pm[i] = p;
        }
        // butterfly: full 512-d dot, broadcast to all lanes
#pragma unroll
        for (int off = 32; off >= 1; off >>= 1) {
#pragma unroll
            for (int i = 0; i < 8; i++) pm[i] += __shfl_xor(pm[i], off, 64);
        }

        float yv[8], s1 = 0.0f, s2 = 0.0f;
#pragma unroll
        for (int j = 0; j < 8; j++) {
            float o = cc[j];
#pragma unroll
            for (int i = 0; i < 8; i++) o += pm[i] * wo[j][i];
            float y = xv[j] + SCALE_C * o;
            yv[j] = y;
            s1 += y;
            s2 += y * y;
        }
#pragma unroll
        for (int off = 32; off >= 1; off >>= 1) {
            s1 += __shfl_xor(s1, off, 64);
            s2 += __shfl_xor(s2, off, 64);
        }
        float mu = s1 * (1.0f / DIMD);
        float var = s2 * (1.0f / DIMD) - mu * mu;
        float rs = rsqrtf(var + EPS_C);

        float ov[8];
#pragma unroll
        for (int j = 0; j < 8; j++) {
            ov[j] = g[j] * (yv[j] - mu) * rs + be[j];
        }
        float* po = out + (rowbase + r) * DIMD + d0;
        *(float4*)po = make_float4(ov[0], ov[1], ov[2], ov[3]);
        *(float4*)(po + 4) = make_float4(ov[4], ov[5], ov[6], ov[7]);
    }
}

extern "C" void kernel_launch(void* const* d_in, const int* in_sizes, int n_in,
                              void* d_out, int out_size, void* d_ws, size_t ws_size,
                              hipStream_t stream) {
    const float* x     = (const float*)d_in[0];
    const float* Wp    = (const float*)d_in[1];
    const float* bp    = (const float*)d_in[2];
    const float* Wm    = (const float*)d_in[3];
    const float* bm    = (const float*)d_in[4];
    const float* Wo    = (const float*)d_in[5];
    const float* bo    = (const float*)d_in[6];
    const float* gamma = (const float*)d_in[7];
    const float* beta  = (const float*)d_in[8];

    float* ws   = (float*)d_ws;
    float* wsum = ws;                 // 4096 floats
    float* wot  = ws + 4096;          // 32768 floats
    float* c2   = ws + 4096 + 32768;  // 4096 floats

    kzero<<<16, 256, 0, stream>>>(wsum, BB * DIMD);
    kmean<<<dim3(128, 8), 256, 0, stream>>>(x, wsum);
    kfold<<<8, 64, 0, stream>>>(wsum, Wm, bm, Wo, bo, bp, wot, c2);
    kmain<<<dim3(128, 8), 256, 0, stream>>>(x, Wp, gamma, beta, wot, c2, (float*)d_out);
}